// Round 8
// baseline (152.791 us; speedup 1.0000x reference)
//
#include <hip/hip_runtime.h>
#include <hip/hip_bf16.h>

#define HW  16384
#define WD  128

#define TS   16            // center tile side
#define HS   18            // halo side
#define HP   (HS * HS)     // 324 halo pixels
#define PRS  20            // padded halo row stride (slots)
#define PLS  360           // plane stride per o4 (ushort4 slots) = 18*20

__device__ __forceinline__ unsigned short f2bf(float f) {
    unsigned int u = __builtin_bit_cast(unsigned int, f);
    u += 0x7FFFu + ((u >> 16) & 1u);          // RNE
    return (unsigned short)(u >> 16);
}
__device__ __forceinline__ float bf2f(unsigned short s) {
    return __builtin_bit_cast(float, (unsigned int)s << 16);
}
__device__ __forceinline__ float ftanh(float v) {
    const float e = __expf(2.0f * v);
    return 1.0f - __fdividef(2.0f, e + 1.0f);
}

// ---- la_nb: neighbor channels = mn[0..7] (group 0 chain), once per pixel ---
__global__ __launch_bounds__(256) void la_nb(
    const float* __restrict__ x,
    const float* __restrict__ w1, const float* __restrict__ b1,
    const float* __restrict__ g1, const float* __restrict__ be1,
    const float* __restrict__ m1, const float* __restrict__ v1,
    const float* __restrict__ w2, const float* __restrict__ b2,
    const float* __restrict__ g2, const float* __restrict__ be2,
    const float* __restrict__ m2, const float* __restrict__ v2,
    float* __restrict__ nb)
{
    const int pix = blockIdx.x * blockDim.x + threadIdx.x;   // 0..16383
    const int b   = blockIdx.y;

    const float* xp = x + (size_t)(b * 256) * HW + pix;      // group 0
    float xv[32];
#pragma unroll
    for (int c = 0; c < 32; ++c) xv[c] = xp[(size_t)c * HW];

    float t0[8];
#pragma unroll
    for (int o = 0; o < 8; ++o) {
        float a = 0.f;
#pragma unroll
        for (int ci = 0; ci < 32; ++ci) a = fmaf(xv[ci], w1[o * 32 + ci], a);
        const float inv = g1[o] * rsqrtf(v1[o] + 1e-5f);
        const float add = be1[o] + (b1[o] - m1[o]) * inv;
        t0[o] = ftanh(fmaf(a, inv, add));
    }

    float* np = nb + (size_t)(b * 8) * HW + pix;
#pragma unroll
    for (int o = 0; o < 8; ++o) {                            // conv2 rows 0..7
        float a = 0.f;
#pragma unroll
        for (int i = 0; i < 8; ++i) a = fmaf(t0[i], w2[o * 8 + i], a);
        const float inv = g2[o] * rsqrtf(v2[o] + 1e-5f);
        const float add = be2[o] + (b2[o] - m2[o]) * inv;
        np[(size_t)o * HW] = fmaf(a, inv, add);
    }
}

// ---- la_fused: v-conv (bf16 LDS) + mask conv + softmax + PV ----------------
// grid = (64 tiles, 16 bg): linear id % 8 == tile%8 -> column-stripe XCD locality
__global__ __launch_bounds__(256, 4) void la_fused(
    const float* __restrict__ x,
    const float* __restrict__ w1, const float* __restrict__ b1,
    const float* __restrict__ g1, const float* __restrict__ be1,
    const float* __restrict__ m1, const float* __restrict__ v1,
    const float* __restrict__ w2, const float* __restrict__ b2,
    const float* __restrict__ g2, const float* __restrict__ be2,
    const float* __restrict__ m2, const float* __restrict__ v2,
    const float* __restrict__ wv, const float* __restrict__ nb,
    float* __restrict__ out)
{
    __shared__ ushort4 vt[8 * PLS];            // v tile, bf16x4: 23040 B
    __shared__ float   nbs[PLS];               // neighbor plane fp32: 1440 B

    const int tid  = threadIdx.x;
    const int tile = blockIdx.x;               // 0..63
    const int bg   = blockIdx.y;
    const int b    = bg >> 3, g = bg & 7;
    const int ty0  = (tile >> 3) * TS;
    const int tx0  = (tile & 7) * TS;

    const float* xg  = x  + (size_t)(b * 256 + g * 32) * HW;
    const float* wvg = wv + g * 1024;
    const float* nbp = nb + (size_t)(b * 8 + g) * HW;

    // ---- phase 1: halo -> v (bf16 LDS) + nb halo (fp32 LDS) ----
    for (int hp = tid; hp < HP; hp += 256) {
        const int hy = hp / HS, hx = hp - hy * HS;
        const int iy = ty0 + hy - 1, ix = tx0 + hx - 1;
        const int slot = hy * PRS + hx;
        if (((unsigned)iy < 128u) && ((unsigned)ix < 128u)) {
            const int po = iy * WD + ix;
            float xv[32];
#pragma unroll
            for (int c = 0; c < 32; ++c) xv[c] = xg[(size_t)c * HW + po];
            nbs[slot] = nbp[po];
#pragma unroll
            for (int o4 = 0; o4 < 8; ++o4) {
                float a0 = 0.f, a1 = 0.f, a2 = 0.f, a3 = 0.f;
                const float* wp = wvg + o4 * 128;
#pragma unroll
                for (int c = 0; c < 32; ++c) {
                    const float xc = xv[c];
                    a0 = fmaf(xc, wp[c],      a0);
                    a1 = fmaf(xc, wp[32 + c], a1);
                    a2 = fmaf(xc, wp[64 + c], a2);
                    a3 = fmaf(xc, wp[96 + c], a3);
                }
                vt[o4 * PLS + slot] = make_ushort4(f2bf(a0), f2bf(a1), f2bf(a2), f2bf(a3));
            }
        } else {
            const ushort4 z = make_ushort4(0, 0, 0, 0);
#pragma unroll
            for (int o4 = 0; o4 < 8; ++o4) vt[o4 * PLS + slot] = z;
            nbs[slot] = 0.f;       // zero-padded neighbor
        }
    }
    __syncthreads();

    // ---- phase 2: one center pixel per thread ----
    const int cy  = tid >> 4, cx = tid & 15;
    const int iy  = ty0 + cy, ix = tx0 + cx;
    const int pix = iy * WD + ix;

    // mask channels mc0..mc0+8 produced by groups pa (k<ksplit) and pb
    const int mc0    = 8 + 9 * g;
    const int pa     = mc0 / 10;
    const int pb     = (mc0 + 8) / 10;
    const int ksplit = 10 - (mc0 - pa * 10);

    float tA[8], tB[8];
    {
        const float* xp  = x  + (size_t)(b * 256 + pa * 32) * HW + pix;
        const float* w1p = w1 + pa * 256;
        float xv[32];
#pragma unroll
        for (int c = 0; c < 32; ++c) xv[c] = xp[(size_t)c * HW];
#pragma unroll
        for (int o = 0; o < 8; ++o) {
            float a = 0.f;
#pragma unroll
            for (int ci = 0; ci < 32; ++ci) a = fmaf(xv[ci], w1p[o * 32 + ci], a);
            const int ch = pa * 8 + o;
            const float inv = g1[ch] * rsqrtf(v1[ch] + 1e-5f);
            const float add = be1[ch] + (b1[ch] - m1[ch]) * inv;
            tA[o] = ftanh(fmaf(a, inv, add));
        }
    }
    if (pb != pa) {
        const float* xp  = x  + (size_t)(b * 256 + pb * 32) * HW + pix;
        const float* w1p = w1 + pb * 256;
        float xv[32];
#pragma unroll
        for (int c = 0; c < 32; ++c) xv[c] = xp[(size_t)c * HW];
#pragma unroll
        for (int o = 0; o < 8; ++o) {
            float a = 0.f;
#pragma unroll
            for (int ci = 0; ci < 32; ++ci) a = fmaf(xv[ci], w1p[o * 32 + ci], a);
            const int ch = pb * 8 + o;
            const float inv = g1[ch] * rsqrtf(v1[ch] + 1e-5f);
            const float add = be1[ch] + (b1[ch] - m1[ch]) * inv;
            tB[o] = ftanh(fmaf(a, inv, add));
        }
    } else {
#pragma unroll
        for (int o = 0; o < 8; ++o) tB[o] = tA[o];
    }

    float lg[9];
    float mx = -1e30f;
#pragma unroll
    for (int k = 0; k < 9; ++k) {
        const int mc = mc0 + k;
        const int p  = (k < ksplit) ? pa : pb;
        const int o  = mc - p * 10;
        const float* w2p = w2 + p * 80 + o * 8;
        float a = 0.f;
#pragma unroll
        for (int i = 0; i < 8; ++i) {
            const float ti = (k < ksplit) ? tA[i] : tB[i];
            a = fmaf(ti, w2p[i], a);
        }
        const float inv = g2[mc] * rsqrtf(v2[mc] + 1e-5f);
        const float add = be2[mc] + (b2[mc] - m2[mc]) * inv;
        const float mask = fmaf(a, inv, add);
        lg[k] = mask + nbs[(cy + k / 3) * PRS + (cx + k % 3)];
        mx = fmaxf(mx, lg[k]);
    }
    float s = 0.f;
#pragma unroll
    for (int k = 0; k < 9; ++k) { lg[k] = __expf(lg[k] - mx); s += lg[k]; }
    const float rs = 1.f / s;
#pragma unroll
    for (int k = 0; k < 9; ++k) lg[k] *= rs;   // OOB taps hit v==0 in LDS

    float* og = out + (size_t)(b * 256 + g * 32) * HW + pix;
#pragma unroll 2
    for (int o4 = 0; o4 < 8; ++o4) {
        const ushort4* vp = vt + o4 * PLS;
        float a0 = 0.f, a1 = 0.f, a2 = 0.f, a3 = 0.f;
#pragma unroll
        for (int k = 0; k < 9; ++k) {
            const int slot = (cy + k / 3) * PRS + (cx + k % 3);
            const ushort4 vv = vp[slot];
            a0 = fmaf(lg[k], bf2f(vv.x), a0);
            a1 = fmaf(lg[k], bf2f(vv.y), a1);
            a2 = fmaf(lg[k], bf2f(vv.z), a2);
            a3 = fmaf(lg[k], bf2f(vv.w), a3);
        }
        __builtin_nontemporal_store(a0, og + (size_t)(o4 * 4 + 0) * HW);
        __builtin_nontemporal_store(a1, og + (size_t)(o4 * 4 + 1) * HW);
        __builtin_nontemporal_store(a2, og + (size_t)(o4 * 4 + 2) * HW);
        __builtin_nontemporal_store(a3, og + (size_t)(o4 * 4 + 3) * HW);
    }
}

extern "C" void kernel_launch(void* const* d_in, const int* in_sizes, int n_in,
                              void* d_out, int out_size, void* d_ws, size_t ws_size,
                              hipStream_t stream)
{
    const float* x   = (const float*)d_in[0];
    const float* w1  = (const float*)d_in[1];
    const float* b1  = (const float*)d_in[2];
    const float* g1  = (const float*)d_in[3];
    const float* be1 = (const float*)d_in[4];
    const float* m1  = (const float*)d_in[5];
    const float* v1  = (const float*)d_in[6];
    const float* w2  = (const float*)d_in[7];
    const float* b2  = (const float*)d_in[8];
    const float* g2  = (const float*)d_in[9];
    const float* be2 = (const float*)d_in[10];
    const float* m2  = (const float*)d_in[11];
    const float* v2  = (const float*)d_in[12];
    const float* wv  = (const float*)d_in[13];

    float* out = (float*)d_out;
    float* nb  = (float*)d_ws;     // 2*8*HW fp32 = 1 MB

    dim3 blk(256);
    dim3 gnb(HW / 256, 2);         // 128 blocks
    dim3 grd(64, 16);              // (tile, bg): id%8 == tile%8 -> XCD stripes

    hipLaunchKernelGGL(la_nb, gnb, blk, 0, stream,
                       x, w1, b1, g1, be1, m1, v1, w2, b2, g2, be2, m2, v2, nb);
    hipLaunchKernelGGL(la_fused, grd, blk, 0, stream,
                       x, w1, b1, g1, be1, m1, v1, w2, b2, g2, be2, m2, v2, wv,
                       nb, out);
}

// Round 10
// 130.635 us; speedup vs baseline: 1.1696x; 1.1696x over previous
//
#include <hip/hip_runtime.h>
#include <hip/hip_bf16.h>

#define HW  16384
#define WD  128

#define TS   16            // center tile side
#define HS   18            // halo side
#define HP   (HS * HS)     // 324 halo pixels
#define PRS  20            // padded halo row stride (slots)
#define PLS  360           // plane stride per c4 (ushort4 slots) = 18*20

__device__ __forceinline__ unsigned short f2bf(float f) {
    unsigned int u = __builtin_bit_cast(unsigned int, f);
    u += 0x7FFFu + ((u >> 16) & 1u);          // RNE
    return (unsigned short)(u >> 16);
}
__device__ __forceinline__ float bf2f(unsigned int s) {
    return __builtin_bit_cast(float, (s & 0xFFFFu) << 16);
}
__device__ __forceinline__ float ftanh(float v) {
    const float e = __expf(2.0f * v);
    return 1.0f - __fdividef(2.0f, e + 1.0f);
}

// ---- la_t: t = tanh(bn1(conv1(x))) for ALL groups (bf16, 8-packed/px),
//            plus nb = mn[0..7] epilogue on the p==0 blocks ------------------
__global__ __launch_bounds__(256) void la_t(
    const float* __restrict__ x,
    const float* __restrict__ w1, const float* __restrict__ b1,
    const float* __restrict__ g1, const float* __restrict__ be1,
    const float* __restrict__ m1, const float* __restrict__ v1,
    const float* __restrict__ w2, const float* __restrict__ b2,
    const float* __restrict__ g2, const float* __restrict__ be2,
    const float* __restrict__ m2, const float* __restrict__ v2,
    unsigned short* __restrict__ t, float* __restrict__ nb)
{
    const int pix = blockIdx.x * blockDim.x + threadIdx.x;   // 0..16383
    const int b   = blockIdx.y;
    const int p   = blockIdx.z;                              // group 0..7

    const float* xp = x + (size_t)(b * 256 + p * 32) * HW + pix;
    float xv[32];
#pragma unroll
    for (int c = 0; c < 32; ++c) xv[c] = xp[(size_t)c * HW];

    const float* w1p = w1 + p * 256;
    float tv[8];
#pragma unroll
    for (int o = 0; o < 8; ++o) {
        float a = 0.f;
#pragma unroll
        for (int ci = 0; ci < 32; ++ci) a = fmaf(xv[ci], w1p[o * 32 + ci], a);
        const int ch = p * 8 + o;
        const float inv = g1[ch] * rsqrtf(v1[ch] + 1e-5f);
        const float add = be1[ch] + (b1[ch] - m1[ch]) * inv;
        tv[o] = ftanh(fmaf(a, inv, add));
    }

    // pack 8 bf16 -> one 16 B store at [b][p][pix][0..7]
    uint4 u;
    u.x = (unsigned)f2bf(tv[0]) | ((unsigned)f2bf(tv[1]) << 16);
    u.y = (unsigned)f2bf(tv[2]) | ((unsigned)f2bf(tv[3]) << 16);
    u.z = (unsigned)f2bf(tv[4]) | ((unsigned)f2bf(tv[5]) << 16);
    u.w = (unsigned)f2bf(tv[6]) | ((unsigned)f2bf(tv[7]) << 16);
    *(uint4*)(t + ((size_t)(b * 8 + p) * HW + pix) * 8) = u;

    if (p == 0) {      // neighbor channels mn[0..7] = bn2(conv2 rows 0..7)
#pragma unroll
        for (int o = 0; o < 8; ++o) {
            float a = 0.f;
#pragma unroll
            for (int i = 0; i < 8; ++i) a = fmaf(tv[i], w2[o * 8 + i], a);
            const float inv = g2[o] * rsqrtf(v2[o] + 1e-5f);
            const float add = be2[o] + (b2[o] - m2[o]) * inv;
            nb[(size_t)(b * 8 + o) * HW + pix] = fmaf(a, inv, add);
        }
    }
}

// ---- la_fused: x-tile copy (bf16 LDS) + mask conv + softmax +
//                out = Wv * (sum_k attn_k x_tap) ------------------------------
// grid = (16 bg, 64 tiles): linear id % 8 == g -> per-XCD x locality
__global__ __launch_bounds__(256, 4) void la_fused(
    const float* __restrict__ x,
    const float* __restrict__ w2, const float* __restrict__ b2,
    const float* __restrict__ g2, const float* __restrict__ be2,
    const float* __restrict__ m2, const float* __restrict__ v2,
    const float* __restrict__ wv,
    const unsigned short* __restrict__ t, const float* __restrict__ nb,
    float* __restrict__ out)
{
    __shared__ ushort4 xt[8 * PLS];            // x tile, bf16x4: 23040 B
    __shared__ float   nbs[PLS];               // neighbor plane fp32: 1440 B

    const int tid  = threadIdx.x;
    const int bg   = blockIdx.x;
    const int tile = blockIdx.y;               // 0..63
    const int b    = bg >> 3, g = bg & 7;
    const int ty0  = (tile >> 3) * TS;
    const int tx0  = (tile & 7) * TS;

    const float* xg  = x  + (size_t)(b * 256 + g * 32) * HW;
    const float* nbp = nb + (size_t)(b * 8 + g) * HW;

    // ---- phase 1: pure copy halo -> bf16 LDS (+ nb halo) ----
    for (int hp = tid; hp < HP; hp += 256) {
        const int hy = hp / HS, hx = hp - hy * HS;
        const int iy = ty0 + hy - 1, ix = tx0 + hx - 1;
        const int slot = hy * PRS + hx;
        if (((unsigned)iy < 128u) && ((unsigned)ix < 128u)) {
            const int po = iy * WD + ix;
            float xv[32];
#pragma unroll
            for (int c = 0; c < 32; ++c) xv[c] = xg[(size_t)c * HW + po];
            nbs[slot] = nbp[po];
#pragma unroll
            for (int c4 = 0; c4 < 8; ++c4)
                xt[c4 * PLS + slot] = make_ushort4(
                    f2bf(xv[c4 * 4 + 0]), f2bf(xv[c4 * 4 + 1]),
                    f2bf(xv[c4 * 4 + 2]), f2bf(xv[c4 * 4 + 3]));
        } else {
            const ushort4 z = make_ushort4(0, 0, 0, 0);
#pragma unroll
            for (int c4 = 0; c4 < 8; ++c4) xt[c4 * PLS + slot] = z;
            nbs[slot] = 0.f;       // zero-padded neighbor
        }
    }
    __syncthreads();

    // ---- phase 2: one center pixel per thread ----
    const int cy  = tid >> 4, cx = tid & 15;
    const int iy  = ty0 + cy, ix = tx0 + cx;
    const int pix = iy * WD + ix;

    // mask channels mc0..mc0+8 produced by groups pa (k<ksplit) and pb
    const int mc0    = 8 + 9 * g;
    const int pa     = mc0 / 10;
    const int pb     = (mc0 + 8) / 10;
    const int ksplit = 10 - (mc0 - pa * 10);

    float tA[8], tB[8];
    {
        const uint4 ua = *(const uint4*)(t + ((size_t)(b * 8 + pa) * HW + pix) * 8);
        tA[0] = bf2f(ua.x); tA[1] = bf2f(ua.x >> 16);
        tA[2] = bf2f(ua.y); tA[3] = bf2f(ua.y >> 16);
        tA[4] = bf2f(ua.z); tA[5] = bf2f(ua.z >> 16);
        tA[6] = bf2f(ua.w); tA[7] = bf2f(ua.w >> 16);
    }
    if (pb != pa) {
        const uint4 ub = *(const uint4*)(t + ((size_t)(b * 8 + pb) * HW + pix) * 8);
        tB[0] = bf2f(ub.x); tB[1] = bf2f(ub.x >> 16);
        tB[2] = bf2f(ub.y); tB[3] = bf2f(ub.y >> 16);
        tB[4] = bf2f(ub.z); tB[5] = bf2f(ub.z >> 16);
        tB[6] = bf2f(ub.w); tB[7] = bf2f(ub.w >> 16);
    } else {
#pragma unroll
        for (int o = 0; o < 8; ++o) tB[o] = tA[o];
    }

    float lg[9];
    float mx = -1e30f;
#pragma unroll
    for (int k = 0; k < 9; ++k) {
        const int mc = mc0 + k;
        const int p  = (k < ksplit) ? pa : pb;
        const int o  = mc - p * 10;
        const float* w2p = w2 + p * 80 + o * 8;
        float a = 0.f;
#pragma unroll
        for (int i = 0; i < 8; ++i) {
            const float ti = (k < ksplit) ? tA[i] : tB[i];
            a = fmaf(ti, w2p[i], a);
        }
        const float inv = g2[mc] * rsqrtf(v2[mc] + 1e-5f);
        const float add = be2[mc] + (b2[mc] - m2[mc]) * inv;
        lg[k] = fmaf(a, inv, add) + nbs[(cy + k / 3) * PRS + (cx + k % 3)];
        mx = fmaxf(mx, lg[k]);
    }
    float ssum = 0.f;
#pragma unroll
    for (int k = 0; k < 9; ++k) { lg[k] = __expf(lg[k] - mx); ssum += lg[k]; }
    const float rs = 1.f / ssum;               // applied once at the store

    // s = sum_k e_k * x_tap  (OOB taps read x==0 from LDS)
    float s[32];
#pragma unroll
    for (int c = 0; c < 32; ++c) s[c] = 0.f;
#pragma unroll
    for (int k = 0; k < 9; ++k) {
        const int slot = (cy + k / 3) * PRS + (cx + k % 3);
        const float e = lg[k];
#pragma unroll
        for (int c4 = 0; c4 < 8; ++c4) {
            const ushort4 xv4 = xt[c4 * PLS + slot];
            s[c4 * 4 + 0] = fmaf(e, bf2f(xv4.x), s[c4 * 4 + 0]);
            s[c4 * 4 + 1] = fmaf(e, bf2f(xv4.y), s[c4 * 4 + 1]);
            s[c4 * 4 + 2] = fmaf(e, bf2f(xv4.z), s[c4 * 4 + 2]);
            s[c4 * 4 + 3] = fmaf(e, bf2f(xv4.w), s[c4 * 4 + 3]);
        }
    }

    // out = rs * (Wv . s)
    const float* wvg = wv + g * 1024;
    float* og = out + (size_t)(b * 256 + g * 32) * HW + pix;
#pragma unroll 4
    for (int o = 0; o < 32; ++o) {
        const float* wp = wvg + o * 32;
        float a = 0.f;
#pragma unroll
        for (int ci = 0; ci < 32; ++ci) a = fmaf(s[ci], wp[ci], a);
        __builtin_nontemporal_store(a * rs, og + (size_t)o * HW);
    }
}

extern "C" void kernel_launch(void* const* d_in, const int* in_sizes, int n_in,
                              void* d_out, int out_size, void* d_ws, size_t ws_size,
                              hipStream_t stream)
{
    const float* x   = (const float*)d_in[0];
    const float* w1  = (const float*)d_in[1];
    const float* b1  = (const float*)d_in[2];
    const float* g1  = (const float*)d_in[3];
    const float* be1 = (const float*)d_in[4];
    const float* m1  = (const float*)d_in[5];
    const float* v1  = (const float*)d_in[6];
    const float* w2  = (const float*)d_in[7];
    const float* b2  = (const float*)d_in[8];
    const float* g2  = (const float*)d_in[9];
    const float* be2 = (const float*)d_in[10];
    const float* m2  = (const float*)d_in[11];
    const float* v2  = (const float*)d_in[12];
    const float* wv  = (const float*)d_in[13];

    float* out = (float*)d_out;
    unsigned short* t = (unsigned short*)d_ws;            // 2*8*HW*8 bf16 = 4.2 MB
    float* nb = (float*)(t + (size_t)2 * 8 * HW * 8);     // 2*8*HW fp32 = 1 MB

    dim3 blk(256);
    dim3 gt(HW / 256, 2, 8);       // 1024 blocks: px x b x group
    dim3 grd(16, 64);              // (bg, tile): id%8==g -> XCD locality

    hipLaunchKernelGGL(la_t, gt, blk, 0, stream,
                       x, w1, b1, g1, be1, m1, v1, w2, b2, g2, be2, m2, v2,
                       t, nb);
    hipLaunchKernelGGL(la_fused, grd, blk, 0, stream,
                       x, w2, b2, g2, be2, m2, v2, wv, t, nb, out);
}